// Round 4
// baseline (299.818 us; speedup 1.0000x reference)
//
#include <hip/hip_runtime.h>
#include <math.h>

#define TN 2048
#define DN 1024
#define NEG_INF (-3.0e38f)

typedef __attribute__((ext_vector_type(8))) _Float16 half8;
typedef __attribute__((ext_vector_type(4))) _Float16 half4v;
typedef __attribute__((ext_vector_type(2))) _Float16 half2v;
typedef __attribute__((ext_vector_type(4))) float f32x4;

__device__ __forceinline__ f32x4 mfma16(half8 a, half8 b, f32x4 c) {
  return __builtin_amdgcn_mfma_f32_16x16x32_f16(a, b, c, 0, 0, 0);
}

// lgkm-only barrier (staging loads survive); full-drain barrier for staging.
#define BAR_LDS()  asm volatile("s_waitcnt lgkmcnt(0)\ns_barrier" ::: "memory")
#define BAR_ALL()  asm volatile("s_waitcnt vmcnt(0) lgkmcnt(0)\ns_barrier" ::: "memory")

// Tile image layout (32 keys x 1024 feats, f16, 64KB):
//   elem_off(key,f) = (f>>4)*512 + perm(key>>2)*64 + (key&3)*16 + (f&15)
//   perm(kg) = (kg&1)*4 + (kg>>1)   (tr_read lane-group lg sees keys 8*lg+j)
__device__ __forceinline__ int img_off(int key, int f) {
  const int kg = key >> 2;
  const int p  = ((kg & 1) << 2) | (kg >> 1);
  return (f >> 4) * 512 + p * 64 + (key & 3) * 16 + (f & 15);
}

// x fp32 [8][2048][1024] -> f16 tile images in ws: [b*64+tile][32768 elems]
__global__ __launch_bounds__(256) void convert_x(const float* __restrict__ x,
                                                 _Float16* __restrict__ w) {
  const long long gid = (long long)blockIdx.x * 256 + threadIdx.x;
  const long long e   = gid * 8;
  const int bt   = (int)(e >> 15);
  const int et   = (int)(e & 32767);
  const int f16b = et >> 9;
  const int p    = (et >> 6) & 7;
  const int row  = (et >> 4) & 3;
  const int col0 = et & 15;
  const int kg   = ((p & 3) << 1) | (p >> 2);    // inverse perm
  const int key  = kg * 4 + row;
  const size_t xoff = ((size_t)bt * 32 + key) * DN + f16b * 16 + col0;
  float4 u0 = *(const float4*)(x + xoff);
  float4 u1 = *(const float4*)(x + xoff + 4);
  half8 h = {(_Float16)u0.x, (_Float16)u0.y, (_Float16)u0.z, (_Float16)u0.w,
             (_Float16)u1.x, (_Float16)u1.y, (_Float16)u1.z, (_Float16)u1.w};
  *(half8*)(w + e) = h;
}

#define ISSUE4(T, O0, O1, O2, O3)                                             \
  asm volatile("ds_read_b64_tr_b16 %0, %4 offset:" O0 "\n\t"                  \
               "ds_read_b64_tr_b16 %1, %4 offset:" O1 "\n\t"                  \
               "ds_read_b64_tr_b16 %2, %4 offset:" O2 "\n\t"                  \
               "ds_read_b64_tr_b16 %3, %4 offset:" O3                         \
               : "=&v"(T[0]), "=&v"(T[1]), "=&v"(T[2]), "=&v"(T[3])           \
               : "v"(ab));

#define MFMA4(T, CT0, CT1)                                                    \
  {                                                                           \
    half8 bf0 = __builtin_shufflevector(T[0], T[1], 0, 1, 2, 3, 4, 5, 6, 7);  \
    half8 bf1 = __builtin_shufflevector(T[2], T[3], 0, 1, 2, 3, 4, 5, 6, 7);  \
    oacc[0][CT0] = mfma16(a0, bf0, oacc[0][CT0]);                             \
    oacc[1][CT0] = mfma16(a1, bf0, oacc[1][CT0]);                             \
    oacc[0][CT1] = mfma16(a0, bf1, oacc[0][CT1]);                             \
    oacc[1][CT1] = mfma16(a1, bf1, oacc[1][CT1]);                             \
  }

// One block = one (batch, q-tile). 512 blocks, qt descending (load balance),
// b = blk&7 -> XCD-pinned batch. LDS ~77.5KB -> 2 blocks/CU; VGPR forced 128.
template <bool WS>
__global__ __launch_bounds__(512, 4)
void attn_gate(const float* __restrict__ x, const _Float16* __restrict__ wsx,
               const float* __restrict__ pla, const float* __restrict__ pls,
               float* __restrict__ out) {
  __shared__ _Float16 Kbuf[32768];            // single K tile image   64KB
  __shared__ _Float16 SredH[4][32][17][2];    // packed S partials     8.5KB
  __shared__ _Float16 Pq[32][40];             // P weights             2.5KB
  __shared__ float m_s[32], l_s[32], corr_s[32], gate_s[32];
  __shared__ int resc_s;

  const int tid = threadIdx.x;
  const int w   = tid >> 6;
  const int l   = tid & 63;
  const int lr  = l & 15;
  const int lg  = l >> 4;
  const int kq  = w & 3;          // k-quarter (256 feats) for QK^T
  const int ti  = w >> 2;         // S row-tile

  const int b  = blockIdx.x & 7;          // batch -> XCD
  const int qt = 63 - (blockIdx.x >> 3);  // long blocks first
  const int qbase = qt * 32;
  const int nkt   = qt + 1;

  const float alpha = log1pf(expf(pla[0]));
  const float sigma = log1pf(expf(pls[0]));

  const float* xb = x + (size_t)b * TN * DN;
  float*       ob = out + (size_t)b * TN * DN;

  // ---- stage tile 0 ----
  if constexpr (WS) {
    const _Float16* t0 = wsx + (size_t)(b * 64 + 0) * 32768;
#pragma unroll
    for (int i = 0; i < 8; ++i)
      __builtin_amdgcn_global_load_lds(
          (const __attribute__((address_space(1))) void*)(t0 + w * 4096 + i * 512 + l * 8),
          (__attribute__((address_space(3))) void*)(&Kbuf[w * 4096 + i * 512]), 16, 0, 0);
  } else {
    const int skey = tid >> 4, sc = tid & 15;
    const float* kp = xb + (size_t)skey * DN + sc * 4;
#pragma unroll
    for (int j = 0; j < 16; ++j) {
      const int f = sc * 4 + 64 * j;
      float4 v = *(const float4*)(kp + 64 * j);
      half4v h = {(_Float16)v.x, (_Float16)v.y, (_Float16)v.z, (_Float16)v.w};
      *(half4v*)&Kbuf[img_off(skey, f)] = h;
    }
  }

  // ---- Q fragments (k-quarter: 8 x half8 = 32 VGPR) ----
  half8 qf[8];
  if constexpr (WS) {
    const _Float16* qtile = wsx + (size_t)(b * 64 + qt) * 32768;
    const int qrow = ti * 16 + lr;
    const int qkg  = qrow >> 2;
    const int qp   = (((qkg & 1) << 2) | (qkg >> 1)) * 64 + (qrow & 3) * 16 + (lg & 1) * 8;
#pragma unroll
    for (int s = 0; s < 8; ++s)
      qf[s] = *(const half8*)&qtile[(kq * 16 + s * 2 + (lg >> 1)) * 512 + qp];
  } else {
    const float* qp = xb + (size_t)(qbase + ti * 16 + lr) * DN + kq * 256 + lg * 8;
#pragma unroll
    for (int s = 0; s < 8; ++s) {
      float4 a = ((const float4*)(qp + s * 32))[0];
      float4 c = ((const float4*)(qp + s * 32))[1];
      half8 h;
      h[0]=(_Float16)a.x; h[1]=(_Float16)a.y; h[2]=(_Float16)a.z; h[3]=(_Float16)a.w;
      h[4]=(_Float16)c.x; h[5]=(_Float16)c.y; h[6]=(_Float16)c.z; h[7]=(_Float16)c.w;
      qf[s] = h;
    }
  }

  f32x4 oacc[2][8];
#pragma unroll
  for (int rt = 0; rt < 2; ++rt)
#pragma unroll
    for (int ct = 0; ct < 8; ++ct)
      oacc[rt][ct] = f32x4{0.f, 0.f, 0.f, 0.f};

  if (tid < 32) { m_s[tid] = NEG_INF; l_s[tid] = 0.0f; }
  if (tid == 0) resc_s = 0;
  BAR_ALL();   // tile 0 staged

  // QK B-frag bases (loop-invariant)
  const int kg0 = lr >> 2;
  const int bk0 = ((((kg0 & 1) << 2) | (kg0 >> 1)) << 6) + (lr & 3) * 16 + (lg & 1) * 8;
  const int kg1 = 4 + (lr >> 2);
  const int bk1 = ((((kg1 & 1) << 2) | (kg1 >> 1)) << 6) + (lr & 3) * 16 + (lg & 1) * 8;

  for (int kt = 0; kt < nkt; ++kt) {
    if (tid == 0) resc_s = 0;   // pre-A write; softmax sets post-A

    // ---- QK^T: wave (ti,kq) -> both 16x16 S-tiles over its k-quarter ----
    {
      f32x4 s0 = f32x4{0.f, 0.f, 0.f, 0.f};
      f32x4 s1 = f32x4{0.f, 0.f, 0.f, 0.f};
#pragma unroll
      for (int s = 0; s < 8; ++s) {
        const int base = (kq * 16 + s * 2 + (lg >> 1)) * 512;
        half8 bf0 = *(const half8*)&Kbuf[base + bk0];
        half8 bf1 = *(const half8*)&Kbuf[base + bk1];
        s0 = mfma16(qf[s], bf0, s0);
        s1 = mfma16(qf[s], bf1, s1);
      }
#pragma unroll
      for (int j = 0; j < 4; ++j) {
        half2v pr2 = {(_Float16)s0[j], (_Float16)s1[j]};
        *(half2v*)&SredH[kq][ti * 16 + lg * 4 + j][lr][0] = pr2;
      }
    }
    BAR_LDS();   // (A) SredH ready

    // ---- online softmax: 16 lanes per q-row ----
    {
      const int r   = tid >> 4;
      const int c0  = tid & 15;
      const int qg  = qbase + r;
      const int kb0 = kt * 32;
      float s0 = 0.f, s1 = 0.f;
#pragma unroll
      for (int k4 = 0; k4 < 4; ++k4) {
        half2v v = *(const half2v*)&SredH[k4][r][c0][0];
        s0 += (float)v[0];
        s1 += (float)v[1];
      }
      s0 *= 0.03125f; s1 *= 0.03125f;
      const bool v0 = (kb0 + c0)      < qg;
      const bool v1 = (kb0 + c0 + 16) < qg;
      if (!v0) s0 = NEG_INF;
      if (!v1) s1 = NEG_INF;
      float tmax = fmaxf(s0, s1);
#pragma unroll
      for (int d = 1; d < 16; d <<= 1) tmax = fmaxf(tmax, __shfl_xor(tmax, d));
      const float m_old = m_s[r];
      const float m_new = fmaxf(m_old, tmax);
      float p0 = v0 ? __expf(s0 - m_new) : 0.0f;
      float p1 = v1 ? __expf(s1 - m_new) : 0.0f;
      float ps = p0 + p1;
#pragma unroll
      for (int d = 1; d < 16; d <<= 1) ps += __shfl_xor(ps, d);
      if (c0 == 0) {
        const float corr = (m_old > 0.5f * NEG_INF) ? __expf(m_old - m_new) : 0.0f;
        m_s[r]    = m_new;
        l_s[r]    = l_s[r] * corr + ps;
        corr_s[r] = corr;
        if (m_new > m_old) resc_s = 1;   // exact: corr==1 when not set
      }
      Pq[r][c0]      = (_Float16)p0;
      Pq[r][c0 + 16] = (_Float16)p1;
    }
    BAR_LDS();   // (B) Pq/corr/resc ready

    // ---- PV: optional rescale, then asm-pipelined tr_read + MFMA ----
    {
      const int doresc = resc_s;
      if (doresc) {
#pragma unroll
        for (int rt = 0; rt < 2; ++rt)
#pragma unroll
          for (int j = 0; j < 4; ++j) {
            const float cr2 = corr_s[rt * 16 + lg * 4 + j];
#pragma unroll
            for (int ct = 0; ct < 8; ++ct) oacc[rt][ct][j] *= cr2;
          }
      }
      const uint32_t pa0 = (uint32_t)(uintptr_t)(void*)&Pq[lr][lg * 8];
      const uint32_t pa1 = (uint32_t)(uintptr_t)(void*)&Pq[16 + lr][lg * 8];
      const uint32_t ab  = (uint32_t)(uintptr_t)(void*)&Kbuf[w * 4096 + l * 4];
      // fence: no compiler LDS ops may remain in flight inside the region
      asm volatile("s_waitcnt lgkmcnt(0)" ::: "memory");
      __builtin_amdgcn_sched_barrier(0);
      half8 a0, a1;
      half4v t0[4], t1[4];
      asm volatile("ds_read_b128 %0, %2\n\t"
                   "ds_read_b128 %1, %3"
                   : "=&v"(a0), "=&v"(a1) : "v"(pa0), "v"(pa1));
      ISSUE4(t0, "0", "512", "1024", "1536");
      ISSUE4(t1, "2048", "2560", "3072", "3584");
      asm volatile("s_waitcnt lgkmcnt(4)" ::: "memory");
      __builtin_amdgcn_sched_barrier(0);
      MFMA4(t0, 0, 1);
      ISSUE4(t0, "4096", "4608", "5120", "5632");
      asm volatile("s_waitcnt lgkmcnt(4)" ::: "memory");
      __builtin_amdgcn_sched_barrier(0);
      MFMA4(t1, 2, 3);
      ISSUE4(t1, "6144", "6656", "7168", "7680");
      asm volatile("s_waitcnt lgkmcnt(4)" ::: "memory");
      __builtin_amdgcn_sched_barrier(0);
      MFMA4(t0, 4, 5);
      asm volatile("s_waitcnt lgkmcnt(0)" ::: "memory");
      __builtin_amdgcn_sched_barrier(0);
      MFMA4(t1, 6, 7);
    }
    BAR_LDS();   // (C) all Kbuf reads done

    // ---- stage tile kt+1 into the single buffer ----
    if (kt + 1 < nkt) {
      if constexpr (WS) {
        const _Float16* tn = wsx + (size_t)(b * 64 + kt + 1) * 32768;
#pragma unroll
        for (int i = 0; i < 8; ++i)
          __builtin_amdgcn_global_load_lds(
              (const __attribute__((address_space(1))) void*)(tn + w * 4096 + i * 512 + l * 8),
              (__attribute__((address_space(3))) void*)(&Kbuf[w * 4096 + i * 512]), 16, 0, 0);
      } else {
        const int skey = tid >> 4, sc = tid & 15;
        const float* kp = xb + (size_t)((kt + 1) * 32 + skey) * DN + sc * 4;
#pragma unroll
        for (int j = 0; j < 16; ++j) {
          const int f = sc * 4 + 64 * j;
          float4 v = *(const float4*)(kp + 64 * j);
          half4v h = {(_Float16)v.x, (_Float16)v.y, (_Float16)v.z, (_Float16)v.w};
          *(half4v*)&Kbuf[img_off(skey, f)] = h;
        }
      }
      BAR_ALL();   // (D) new tile visible before next QK
    }
  }

  // ---- epilogue: per-row <x,O>, |x|^2, |O|^2 ----
  {
    float* ered = (float*)&SredH[0][0][0][0];   // reuse (4KB of 8.5KB)
#pragma unroll
    for (int rt = 0; rt < 2; ++rt)
#pragma unroll
      for (int j = 0; j < 4; ++j) {
        const int row = rt * 16 + lg * 4 + j;
        const float* xr = xb + (size_t)(qbase + row) * DN + w * 128 + lr;
        float a1 = 0.f, a2 = 0.f, a3 = 0.f;
#pragma unroll
        for (int ct = 0; ct < 8; ++ct) {
          const float xv = xr[ct * 16];
          const float ov = oacc[rt][ct][j];
          a1 += xv * ov; a2 += xv * xv; a3 += ov * ov;
        }
#pragma unroll
        for (int d = 1; d < 16; d <<= 1) {
          a1 += __shfl_xor(a1, d);
          a2 += __shfl_xor(a2, d);
          a3 += __shfl_xor(a3, d);
        }
        if (lr == 0) {
          float* e = ered + (row * 8 + w) * 4;
          e[0] = a1; e[1] = a2; e[2] = a3;
        }
      }
  }
  __syncthreads();
  if (tid < 32) {
    const float* ered = (const float*)&SredH[0][0][0][0];
    float SxO = 0.f, Sxx = 0.f, SOO = 0.f;
#pragma unroll
    for (int wv = 0; wv < 8; ++wv) {
      const float* e = ered + (tid * 8 + wv) * 4;
      SxO += e[0]; Sxx += e[1]; SOO += e[2];
    }
    const float lden = l_s[tid];
    float cosv = 0.0f;
    if (lden > 0.0f) {
      const float nx = fmaxf(sqrtf(Sxx), 1e-12f);
      const float nc = fmaxf(sqrtf(SOO) / lden, 1e-12f);
      cosv = (SxO / lden) / (nx * nc);
    }
    float nov = fminf(fmaxf(1.0f - cosv, 0.0f), 2.0f) * 0.5f;
    gate_s[tid] = 1.0f + alpha * tanhf(sigma * nov);
  }
  __syncthreads();
  {
#pragma unroll
    for (int rt = 0; rt < 2; ++rt)
#pragma unroll
      for (int j = 0; j < 4; ++j) {
        const int row = rt * 16 + lg * 4 + j;
        const float g = gate_s[row];
        const float* xr = xb + (size_t)(qbase + row) * DN + w * 128 + lr;
        float* orow     = ob + (size_t)(qbase + row) * DN + w * 128 + lr;
#pragma unroll
        for (int ct = 0; ct < 8; ++ct) {
          const float z = xr[ct * 16] * g;
          const float u = 0.7978845608028654f * (z + 0.044715f * z * z * z);
          orow[ct * 16] = 0.5f * z * (1.0f + tanhf(u));
        }
      }
  }
}

extern "C" void kernel_launch(void* const* d_in, const int* in_sizes, int n_in,
                              void* d_out, int out_size, void* d_ws, size_t ws_size,
                              hipStream_t stream) {
  const float* x  = (const float*)d_in[0];
  const float* la = (const float*)d_in[1];
  const float* ls = (const float*)d_in[2];
  float* out = (float*)d_out;
  const size_t need = (size_t)8 * 64 * 32768 * 2;   // 32 MB f16 tile images
  if (ws_size >= need) {
    convert_x<<<dim3(8192), dim3(256), 0, stream>>>(x, (_Float16*)d_ws);
    attn_gate<true><<<dim3(512), dim3(512), 0, stream>>>(
        x, (const _Float16*)d_ws, la, ls, out);
  } else {
    attn_gate<false><<<dim3(512), dim3(512), 0, stream>>>(
        x, (const _Float16*)nullptr, la, ls, out);
  }
}

// Round 5
// 252.703 us; speedup vs baseline: 1.1864x; 1.1864x over previous
//
#include <hip/hip_runtime.h>
#include <math.h>

#define TN 2048
#define DN 1024
#define NEG_INF (-3.0e38f)

typedef __attribute__((ext_vector_type(8))) _Float16 half8;
typedef __attribute__((ext_vector_type(4))) _Float16 half4v;
typedef __attribute__((ext_vector_type(2))) _Float16 half2v;
typedef __attribute__((ext_vector_type(4))) float f32x4;

__device__ __forceinline__ f32x4 mfma16(half8 a, half8 b, f32x4 c) {
  return __builtin_amdgcn_mfma_f32_16x16x32_f16(a, b, c, 0, 0, 0);
}

// lgkm-only barrier (staging loads survive); full-drain barrier for staging.
#define BAR_LDS()  asm volatile("s_waitcnt lgkmcnt(0)\ns_barrier" ::: "memory")
#define BAR_ALL()  asm volatile("s_waitcnt vmcnt(0) lgkmcnt(0)\ns_barrier" ::: "memory")

// Tile image layout (32 keys x 1024 feats, f16, 64KB):
//   elem_off(key,f) = (f>>4)*512 + perm(key>>2)*64 + (key&3)*16 + (f&15)
//   perm(kg) = (kg&1)*4 + (kg>>1)   (tr_read lane-group lg sees keys 8*lg+j)
__device__ __forceinline__ int img_off(int key, int f) {
  const int kg = key >> 2;
  const int p  = ((kg & 1) << 2) | (kg >> 1);
  return (f >> 4) * 512 + p * 64 + (key & 3) * 16 + (f & 15);
}

// x fp32 [8][2048][1024] -> f16 tile images in ws: [b*64+tile][32768 elems]
__global__ __launch_bounds__(256) void convert_x(const float* __restrict__ x,
                                                 _Float16* __restrict__ w) {
  const long long gid = (long long)blockIdx.x * 256 + threadIdx.x;
  const long long e   = gid * 8;
  const int bt   = (int)(e >> 15);
  const int et   = (int)(e & 32767);
  const int f16b = et >> 9;
  const int p    = (et >> 6) & 7;
  const int row  = (et >> 4) & 3;
  const int col0 = et & 15;
  const int kg   = ((p & 3) << 1) | (p >> 2);    // inverse perm
  const int key  = kg * 4 + row;
  const size_t xoff = ((size_t)bt * 32 + key) * DN + f16b * 16 + col0;
  float4 u0 = *(const float4*)(x + xoff);
  float4 u1 = *(const float4*)(x + xoff + 4);
  half8 h = {(_Float16)u0.x, (_Float16)u0.y, (_Float16)u0.z, (_Float16)u0.w,
             (_Float16)u1.x, (_Float16)u1.y, (_Float16)u1.z, (_Float16)u1.w};
  *(half8*)(w + e) = h;
}

#define ISSUE4(T, O0, O1, O2, O3)                                             \
  asm volatile("ds_read_b64_tr_b16 %0, %4 offset:" O0 "\n\t"                  \
               "ds_read_b64_tr_b16 %1, %4 offset:" O1 "\n\t"                  \
               "ds_read_b64_tr_b16 %2, %4 offset:" O2 "\n\t"                  \
               "ds_read_b64_tr_b16 %3, %4 offset:" O3                         \
               : "=&v"(T[0]), "=&v"(T[1]), "=&v"(T[2]), "=&v"(T[3])           \
               : "v"(ab));

#define MFMA4(T, CT0, CT1)                                                    \
  {                                                                           \
    half8 bf0 = __builtin_shufflevector(T[0], T[1], 0, 1, 2, 3, 4, 5, 6, 7);  \
    half8 bf1 = __builtin_shufflevector(T[2], T[3], 0, 1, 2, 3, 4, 5, 6, 7);  \
    oacc[0][CT0] = mfma16(a0, bf0, oacc[0][CT0]);                             \
    oacc[1][CT0] = mfma16(a1, bf0, oacc[1][CT0]);                             \
    oacc[0][CT1] = mfma16(a0, bf1, oacc[0][CT1]);                             \
    oacc[1][CT1] = mfma16(a1, bf1, oacc[1][CT1]);                             \
  }

// One block = one (batch, q-tile). 512 blocks; b = blk&7 -> XCD-pinned batch.
// Snake pairing: co-resident blocks (i, i+256) get qt summing to 63 -> each
// CU's two blocks do exactly 65 K-tiles total (load balance).
// LDS ~77.8KB + VGPR<=128 -> 2 blocks/CU.
template <bool WS>
__global__ __launch_bounds__(512)   // no min-waves hint: R4's (512,4) forced
                                    // 64 VGPR + spills (WRITE_SIZE +59MB)
void attn_gate(const float* __restrict__ x, const _Float16* __restrict__ wsx,
               const float* __restrict__ pla, const float* __restrict__ pls,
               float* __restrict__ out) {
  __shared__ _Float16 Kbuf[32768];            // single K tile image   64KB
  __shared__ _Float16 SredH[4][32][17][2];    // packed S partials     8.5KB
  __shared__ _Float16 Pq[32][40];             // P weights             2.5KB
  __shared__ float m_s[32], l_s[32], corr_s[32], gate_s[32];
  __shared__ int resc_s;

  const int tid = threadIdx.x;
  const int w   = tid >> 6;
  const int l   = tid & 63;
  const int lr  = l & 15;
  const int lg  = l >> 4;
  const int kq  = w & 3;          // k-quarter (256 feats) for QK^T
  const int ti  = w >> 2;         // S row-tile

  const int b  = blockIdx.x & 7;          // batch -> XCD
  const int p_ = blockIdx.x >> 3;         // 0..63
  const int qt = (p_ < 32) ? (63 - p_) : (p_ - 32);   // snake pairing
  const int qbase = qt * 32;
  const int nkt   = qt + 1;

  const float alpha = log1pf(expf(pla[0]));
  const float sigma = log1pf(expf(pls[0]));

  const float* xb = x + (size_t)b * TN * DN;
  float*       ob = out + (size_t)b * TN * DN;

  // ---- stage tile 0 ----
  if constexpr (WS) {
    const _Float16* t0 = wsx + (size_t)(b * 64 + 0) * 32768;
#pragma unroll
    for (int i = 0; i < 8; ++i)
      __builtin_amdgcn_global_load_lds(
          (const __attribute__((address_space(1))) void*)(t0 + w * 4096 + i * 512 + l * 8),
          (__attribute__((address_space(3))) void*)(&Kbuf[w * 4096 + i * 512]), 16, 0, 0);
  } else {
    const int skey = tid >> 4, sc = tid & 15;
    const float* kp = xb + (size_t)skey * DN + sc * 4;
#pragma unroll
    for (int j = 0; j < 16; ++j) {
      const int f = sc * 4 + 64 * j;
      float4 v = *(const float4*)(kp + 64 * j);
      half4v h = {(_Float16)v.x, (_Float16)v.y, (_Float16)v.z, (_Float16)v.w};
      *(half4v*)&Kbuf[img_off(skey, f)] = h;
    }
  }

  // ---- Q fragments (k-quarter: 8 x half8 = 32 VGPR) ----
  half8 qf[8];
  if constexpr (WS) {
    const _Float16* qtile = wsx + (size_t)(b * 64 + qt) * 32768;
    const int qrow = ti * 16 + lr;
    const int qkg  = qrow >> 2;
    const int qp   = (((qkg & 1) << 2) | (qkg >> 1)) * 64 + (qrow & 3) * 16 + (lg & 1) * 8;
#pragma unroll
    for (int s = 0; s < 8; ++s)
      qf[s] = *(const half8*)&qtile[(kq * 16 + s * 2 + (lg >> 1)) * 512 + qp];
  } else {
    const float* qp = xb + (size_t)(qbase + ti * 16 + lr) * DN + kq * 256 + lg * 8;
#pragma unroll
    for (int s = 0; s < 8; ++s) {
      float4 a = ((const float4*)(qp + s * 32))[0];
      float4 c = ((const float4*)(qp + s * 32))[1];
      half8 h;
      h[0]=(_Float16)a.x; h[1]=(_Float16)a.y; h[2]=(_Float16)a.z; h[3]=(_Float16)a.w;
      h[4]=(_Float16)c.x; h[5]=(_Float16)c.y; h[6]=(_Float16)c.z; h[7]=(_Float16)c.w;
      qf[s] = h;
    }
  }

  f32x4 oacc[2][8];
#pragma unroll
  for (int rt = 0; rt < 2; ++rt)
#pragma unroll
    for (int ct = 0; ct < 8; ++ct)
      oacc[rt][ct] = f32x4{0.f, 0.f, 0.f, 0.f};

  if (tid < 32) { m_s[tid] = NEG_INF; l_s[tid] = 0.0f; }
  if (tid == 0) resc_s = 0;
  BAR_ALL();   // tile 0 staged

  // QK B-frag bases (loop-invariant)
  const int kg0 = lr >> 2;
  const int bk0 = ((((kg0 & 1) << 2) | (kg0 >> 1)) << 6) + (lr & 3) * 16 + (lg & 1) * 8;
  const int kg1 = 4 + (lr >> 2);
  const int bk1 = ((((kg1 & 1) << 2) | (kg1 >> 1)) << 6) + (lr & 3) * 16 + (lg & 1) * 8;

  for (int kt = 0; kt < nkt; ++kt) {
    if (tid == 0) resc_s = 0;   // pre-A write; softmax sets post-A

    // ---- QK^T: wave (ti,kq) -> both 16x16 S-tiles over its k-quarter ----
    {
      f32x4 s0 = f32x4{0.f, 0.f, 0.f, 0.f};
      f32x4 s1 = f32x4{0.f, 0.f, 0.f, 0.f};
#pragma unroll
      for (int s = 0; s < 8; ++s) {
        const int base = (kq * 16 + s * 2 + (lg >> 1)) * 512;
        half8 bf0 = *(const half8*)&Kbuf[base + bk0];
        half8 bf1 = *(const half8*)&Kbuf[base + bk1];
        s0 = mfma16(qf[s], bf0, s0);
        s1 = mfma16(qf[s], bf1, s1);
      }
#pragma unroll
      for (int j = 0; j < 4; ++j) {
        half2v pr2 = {(_Float16)s0[j], (_Float16)s1[j]};
        *(half2v*)&SredH[kq][ti * 16 + lg * 4 + j][lr][0] = pr2;
      }
    }
    BAR_LDS();   // (A) SredH ready

    // ---- online softmax: 16 lanes per q-row ----
    {
      const int r   = tid >> 4;
      const int c0  = tid & 15;
      const int qg  = qbase + r;
      const int kb0 = kt * 32;
      float s0 = 0.f, s1 = 0.f;
#pragma unroll
      for (int k4 = 0; k4 < 4; ++k4) {
        half2v v = *(const half2v*)&SredH[k4][r][c0][0];
        s0 += (float)v[0];
        s1 += (float)v[1];
      }
      s0 *= 0.03125f; s1 *= 0.03125f;
      const bool v0 = (kb0 + c0)      < qg;
      const bool v1 = (kb0 + c0 + 16) < qg;
      if (!v0) s0 = NEG_INF;
      if (!v1) s1 = NEG_INF;
      float tmax = fmaxf(s0, s1);
#pragma unroll
      for (int d = 1; d < 16; d <<= 1) tmax = fmaxf(tmax, __shfl_xor(tmax, d));
      const float m_old = m_s[r];
      const float m_new = fmaxf(m_old, tmax);
      float p0 = v0 ? __expf(s0 - m_new) : 0.0f;
      float p1 = v1 ? __expf(s1 - m_new) : 0.0f;
      float ps = p0 + p1;
#pragma unroll
      for (int d = 1; d < 16; d <<= 1) ps += __shfl_xor(ps, d);
      if (c0 == 0) {
        const float corr = (m_old > 0.5f * NEG_INF) ? __expf(m_old - m_new) : 0.0f;
        m_s[r]    = m_new;
        l_s[r]    = l_s[r] * corr + ps;
        corr_s[r] = corr;
        if (m_new > m_old) resc_s = 1;   // exact: corr==1 when not set
      }
      Pq[r][c0]      = (_Float16)p0;
      Pq[r][c0 + 16] = (_Float16)p1;
    }
    BAR_LDS();   // (B) Pq/corr/resc ready

    // ---- PV: optional rescale, then asm-pipelined tr_read + MFMA ----
    {
      const int doresc = resc_s;
      if (doresc) {
#pragma unroll
        for (int rt = 0; rt < 2; ++rt)
#pragma unroll
          for (int j = 0; j < 4; ++j) {
            const float cr2 = corr_s[rt * 16 + lg * 4 + j];
#pragma unroll
            for (int ct = 0; ct < 8; ++ct) oacc[rt][ct][j] *= cr2;
          }
      }
      const uint32_t pa0 = (uint32_t)(uintptr_t)(void*)&Pq[lr][lg * 8];
      const uint32_t pa1 = (uint32_t)(uintptr_t)(void*)&Pq[16 + lr][lg * 8];
      const uint32_t ab  = (uint32_t)(uintptr_t)(void*)&Kbuf[w * 4096 + l * 4];
      // fence: no compiler LDS ops may remain in flight inside the region
      asm volatile("s_waitcnt lgkmcnt(0)" ::: "memory");
      __builtin_amdgcn_sched_barrier(0);
      half8 a0, a1;
      half4v t0[4], t1[4];
      asm volatile("ds_read_b128 %0, %2\n\t"
                   "ds_read_b128 %1, %3"
                   : "=&v"(a0), "=&v"(a1) : "v"(pa0), "v"(pa1));
      ISSUE4(t0, "0", "512", "1024", "1536");
      ISSUE4(t1, "2048", "2560", "3072", "3584");
      asm volatile("s_waitcnt lgkmcnt(4)" ::: "memory");
      __builtin_amdgcn_sched_barrier(0);
      MFMA4(t0, 0, 1);
      ISSUE4(t0, "4096", "4608", "5120", "5632");
      asm volatile("s_waitcnt lgkmcnt(4)" ::: "memory");
      __builtin_amdgcn_sched_barrier(0);
      MFMA4(t1, 2, 3);
      ISSUE4(t1, "6144", "6656", "7168", "7680");
      asm volatile("s_waitcnt lgkmcnt(4)" ::: "memory");
      __builtin_amdgcn_sched_barrier(0);
      MFMA4(t0, 4, 5);
      asm volatile("s_waitcnt lgkmcnt(0)" ::: "memory");
      __builtin_amdgcn_sched_barrier(0);
      MFMA4(t1, 6, 7);
    }
    BAR_LDS();   // (C) all Kbuf reads done

    // ---- stage tile kt+1 into the single buffer ----
    if (kt + 1 < nkt) {
      if constexpr (WS) {
        const _Float16* tn = wsx + (size_t)(b * 64 + kt + 1) * 32768;
#pragma unroll
        for (int i = 0; i < 8; ++i)
          __builtin_amdgcn_global_load_lds(
              (const __attribute__((address_space(1))) void*)(tn + w * 4096 + i * 512 + l * 8),
              (__attribute__((address_space(3))) void*)(&Kbuf[w * 4096 + i * 512]), 16, 0, 0);
      } else {
        const int skey = tid >> 4, sc = tid & 15;
        const float* kp = xb + (size_t)((kt + 1) * 32 + skey) * DN + sc * 4;
#pragma unroll
        for (int j = 0; j < 16; ++j) {
          const int f = sc * 4 + 64 * j;
          float4 v = *(const float4*)(kp + 64 * j);
          half4v h = {(_Float16)v.x, (_Float16)v.y, (_Float16)v.z, (_Float16)v.w};
          *(half4v*)&Kbuf[img_off(skey, f)] = h;
        }
      }
      BAR_ALL();   // (D) new tile visible before next QK
    }
  }

  // ---- epilogue: per-row <x,O>, |x|^2, |O|^2 ----
  {
    float* ered = (float*)&SredH[0][0][0][0];   // reuse (4KB of 8.5KB)
#pragma unroll
    for (int rt = 0; rt < 2; ++rt)
#pragma unroll
      for (int j = 0; j < 4; ++j) {
        const int row = rt * 16 + lg * 4 + j;
        const float* xr = xb + (size_t)(qbase + row) * DN + w * 128 + lr;
        float a1 = 0.f, a2 = 0.f, a3 = 0.f;
#pragma unroll
        for (int ct = 0; ct < 8; ++ct) {
          const float xv = xr[ct * 16];
          const float ov = oacc[rt][ct][j];
          a1 += xv * ov; a2 += xv * xv; a3 += ov * ov;
        }
#pragma unroll
        for (int d = 1; d < 16; d <<= 1) {
          a1 += __shfl_xor(a1, d);
          a2 += __shfl_xor(a2, d);
          a3 += __shfl_xor(a3, d);
        }
        if (lr == 0) {
          float* e = ered + (row * 8 + w) * 4;
          e[0] = a1; e[1] = a2; e[2] = a3;
        }
      }
  }
  __syncthreads();
  if (tid < 32) {
    const float* ered = (const float*)&SredH[0][0][0][0];
    float SxO = 0.f, Sxx = 0.f, SOO = 0.f;
#pragma unroll
    for (int wv = 0; wv < 8; ++wv) {
      const float* e = ered + (tid * 8 + wv) * 4;
      SxO += e[0]; Sxx += e[1]; SOO += e[2];
    }
    const float lden = l_s[tid];
    float cosv = 0.0f;
    if (lden > 0.0f) {
      const float nx = fmaxf(sqrtf(Sxx), 1e-12f);
      const float nc = fmaxf(sqrtf(SOO) / lden, 1e-12f);
      cosv = (SxO / lden) / (nx * nc);
    }
    float nov = fminf(fmaxf(1.0f - cosv, 0.0f), 2.0f) * 0.5f;
    gate_s[tid] = 1.0f + alpha * tanhf(sigma * nov);
  }
  __syncthreads();
  {
#pragma unroll
    for (int rt = 0; rt < 2; ++rt)
#pragma unroll
      for (int j = 0; j < 4; ++j) {
        const int row = rt * 16 + lg * 4 + j;
        const float g = gate_s[row];
        const float* xr = xb + (size_t)(qbase + row) * DN + w * 128 + lr;
        float* orow     = ob + (size_t)(qbase + row) * DN + w * 128 + lr;
#pragma unroll
        for (int ct = 0; ct < 8; ++ct) {
          const float z = xr[ct * 16] * g;
          const float u = 0.7978845608028654f * (z + 0.044715f * z * z * z);
          orow[ct * 16] = 0.5f * z * (1.0f + tanhf(u));
        }
      }
  }
}

extern "C" void kernel_launch(void* const* d_in, const int* in_sizes, int n_in,
                              void* d_out, int out_size, void* d_ws, size_t ws_size,
                              hipStream_t stream) {
  const float* x  = (const float*)d_in[0];
  const float* la = (const float*)d_in[1];
  const float* ls = (const float*)d_in[2];
  float* out = (float*)d_out;
  const size_t need = (size_t)8 * 64 * 32768 * 2;   // 32 MB f16 tile images
  if (ws_size >= need) {
    convert_x<<<dim3(8192), dim3(256), 0, stream>>>(x, (_Float16*)d_ws);
    attn_gate<true><<<dim3(512), dim3(512), 0, stream>>>(
        x, (const _Float16*)d_ws, la, ls, out);
  } else {
    attn_gate<false><<<dim3(512), dim3(512), 0, stream>>>(
        x, (const _Float16*)nullptr, la, ls, out);
  }
}

// Round 6
// 217.409 us; speedup vs baseline: 1.3790x; 1.1623x over previous
//
#include <hip/hip_runtime.h>
#include <math.h>

#define TN 2048
#define DN 1024
#define NEG_INF (-3.0e38f)

typedef __attribute__((ext_vector_type(8))) _Float16 half8;
typedef __attribute__((ext_vector_type(4))) _Float16 half4v;
typedef __attribute__((ext_vector_type(2))) _Float16 half2v;
typedef __attribute__((ext_vector_type(4))) float f32x4;

__device__ __forceinline__ f32x4 mfma16(half8 a, half8 b, f32x4 c) {
  return __builtin_amdgcn_mfma_f32_16x16x32_f16(a, b, c, 0, 0, 0);
}

// lgkm-only barrier (async staging survives); BAR_ALL drains vmcnt too.
#define BAR_LDS()  asm volatile("s_waitcnt lgkmcnt(0)\ns_barrier" ::: "memory")
#define BAR_ALL()  asm volatile("s_waitcnt vmcnt(0) lgkmcnt(0)\ns_barrier" ::: "memory")

// Tile image layout (32 keys x 1024 feats, f16, 64KB):
//   elem_off(key,f) = (f>>4)*512 + perm(key>>2)*64 + (key&3)*16 + (f&15)
//   perm(kg) = (kg&1)*4 + (kg>>1)   (tr_read lane-group lg sees keys 8*lg+j)
__device__ __forceinline__ int img_off(int key, int f) {
  const int kg = key >> 2;
  const int p  = ((kg & 1) << 2) | (kg >> 1);
  return (f >> 4) * 512 + p * 64 + (key & 3) * 16 + (f & 15);
}

// x fp32 [8][2048][1024] -> f16 tile images in ws: [b*64+tile][32768 elems]
__global__ __launch_bounds__(256) void convert_x(const float* __restrict__ x,
                                                 _Float16* __restrict__ w) {
  const long long gid = (long long)blockIdx.x * 256 + threadIdx.x;
  const long long e   = gid * 8;
  const int bt   = (int)(e >> 15);
  const int et   = (int)(e & 32767);
  const int f16b = et >> 9;
  const int p    = (et >> 6) & 7;
  const int row  = (et >> 4) & 3;
  const int col0 = et & 15;
  const int kg   = ((p & 3) << 1) | (p >> 2);    // inverse perm
  const int key  = kg * 4 + row;
  const size_t xoff = ((size_t)bt * 32 + key) * DN + f16b * 16 + col0;
  float4 u0 = *(const float4*)(x + xoff);
  float4 u1 = *(const float4*)(x + xoff + 4);
  half8 h = {(_Float16)u0.x, (_Float16)u0.y, (_Float16)u0.z, (_Float16)u0.w,
             (_Float16)u1.x, (_Float16)u1.y, (_Float16)u1.z, (_Float16)u1.w};
  *(half8*)(w + e) = h;
}

#define ISSUE4(T, O0, O1, O2, O3)                                             \
  asm volatile("ds_read_b64_tr_b16 %0, %4 offset:" O0 "\n\t"                  \
               "ds_read_b64_tr_b16 %1, %4 offset:" O1 "\n\t"                  \
               "ds_read_b64_tr_b16 %2, %4 offset:" O2 "\n\t"                  \
               "ds_read_b64_tr_b16 %3, %4 offset:" O3                         \
               : "=&v"(T[0]), "=&v"(T[1]), "=&v"(T[2]), "=&v"(T[3])           \
               : "v"(ab));

#define MFMA4(T, CT0, CT1)                                                    \
  {                                                                           \
    half8 bf0 = __builtin_shufflevector(T[0], T[1], 0, 1, 2, 3, 4, 5, 6, 7);  \
    half8 bf1 = __builtin_shufflevector(T[2], T[3], 0, 1, 2, 3, 4, 5, 6, 7);  \
    oacc[0][CT0] = mfma16(a0, bf0, oacc[0][CT0]);                             \
    oacc[1][CT0] = mfma16(a1, bf0, oacc[1][CT0]);                             \
    oacc[0][CT1] = mfma16(a0, bf1, oacc[0][CT1]);                             \
    oacc[1][CT1] = mfma16(a1, bf1, oacc[1][CT1]);                             \
  }

// One block = one (batch, pair {pr,63-pr}) with hv loop -> 65 iters/block.
// 16 waves (1024 thr): QK 8-way k-split (qf=16 VGPR), per-wave 64-feat O
// slice (oacc=32 AGPR) -> ~120 unified regs -> 16 waves/CU co-resident.
// LDS: double-buffered K (128KB) + Sred 17.4KB + Pq -> ~148KB, 1 block/CU.
template <bool WS>
__global__ __launch_bounds__(1024)
void attn_gate(const float* __restrict__ x, const _Float16* __restrict__ wsx,
               const float* __restrict__ pla, const float* __restrict__ pls,
               float* __restrict__ out) {
  __shared__ _Float16 Kbuf[2][32768];         // dbuf K tile images    128KB
  __shared__ _Float16 SredH[8][32][17][2];    // packed S partials     17.4KB
  __shared__ _Float16 Pq[32][40];             // P weights             2.5KB
  __shared__ float m_s[32], l_s[32], corr_s[32], gate_s[32];
  __shared__ int resc_s;

  const int tid = threadIdx.x;
  const int w   = tid >> 6;       // wave 0..15
  const int l   = tid & 63;
  const int lr  = l & 15;
  const int lg  = l >> 4;
  const int kq  = w & 7;          // k-eighth (128 feats) for QK^T
  const int ti  = w >> 3;         // S row-tile

  const int b  = blockIdx.x & 7;          // batch -> XCD
  const int pr = blockIdx.x >> 3;         // pair 0..31

  const float alpha = log1pf(expf(pla[0]));
  const float sigma = log1pf(expf(pls[0]));

  const float* xb = x + (size_t)b * TN * DN;
  float*       ob = out + (size_t)b * TN * DN;

  // QK B-frag bases (loop-invariant)
  const int kg0 = lr >> 2;
  const int bk0 = ((((kg0 & 1) << 2) | (kg0 >> 1)) << 6) + (lr & 3) * 16 + (lg & 1) * 8;
  const int kg1 = 4 + (lr >> 2);
  const int bk1 = ((((kg1 & 1) << 2) | (kg1 >> 1)) << 6) + (lr & 3) * 16 + (lg & 1) * 8;

  for (int hv = 0; hv < 2; ++hv) {
    const int qt    = hv ? (63 - pr) : pr;
    const int qbase = qt * 32;
    const int nkt   = qt + 1;

    // ---- stage tiles 0 (and 1) ----
    if constexpr (WS) {
      const _Float16* t0 = wsx + (size_t)(b * 64 + 0) * 32768;
#pragma unroll
      for (int i = 0; i < 4; ++i)
        __builtin_amdgcn_global_load_lds(
            (const __attribute__((address_space(1))) void*)(t0 + w * 2048 + i * 512 + l * 8),
            (__attribute__((address_space(3))) void*)(&Kbuf[0][w * 2048 + i * 512]), 16, 0, 0);
      if (nkt > 1) {
        const _Float16* t1 = wsx + (size_t)(b * 64 + 1) * 32768;
#pragma unroll
        for (int i = 0; i < 4; ++i)
          __builtin_amdgcn_global_load_lds(
              (const __attribute__((address_space(1))) void*)(t1 + w * 2048 + i * 512 + l * 8),
              (__attribute__((address_space(3))) void*)(&Kbuf[1][w * 2048 + i * 512]), 16, 0, 0);
      }
    } else {
      const int skey = tid >> 5, sc = tid & 31;
      for (int t = 0; t < (nkt > 1 ? 2 : 1); ++t) {
        const float* kp = xb + (size_t)(t * 32 + skey) * DN + sc * 4;
#pragma unroll
        for (int j = 0; j < 8; ++j) {
          const int f = sc * 4 + 128 * j;
          float4 v = *(const float4*)(kp + 128 * j);
          half4v h = {(_Float16)v.x, (_Float16)v.y, (_Float16)v.z, (_Float16)v.w};
          *(half4v*)&Kbuf[t][img_off(skey, f)] = h;
        }
      }
    }

    // ---- Q fragments (k-eighth: 4 x half8 = 16 VGPR) ----
    half8 qf[4];
    if constexpr (WS) {
      const _Float16* qtile = wsx + (size_t)(b * 64 + qt) * 32768;
      const int qrow = ti * 16 + lr;
      const int qkg  = qrow >> 2;
      const int qp   = (((qkg & 1) << 2) | (qkg >> 1)) * 64 + (qrow & 3) * 16 + (lg & 1) * 8;
#pragma unroll
      for (int s = 0; s < 4; ++s)
        qf[s] = *(const half8*)&qtile[(kq * 8 + s * 2 + (lg >> 1)) * 512 + qp];
    } else {
      const float* qp = xb + (size_t)(qbase + ti * 16 + lr) * DN + kq * 128 + lg * 8;
#pragma unroll
      for (int s = 0; s < 4; ++s) {
        float4 a = ((const float4*)(qp + s * 32))[0];
        float4 c = ((const float4*)(qp + s * 32))[1];
        half8 h;
        h[0]=(_Float16)a.x; h[1]=(_Float16)a.y; h[2]=(_Float16)a.z; h[3]=(_Float16)a.w;
        h[4]=(_Float16)c.x; h[5]=(_Float16)c.y; h[6]=(_Float16)c.z; h[7]=(_Float16)c.w;
        qf[s] = h;
      }
    }

    f32x4 oacc[2][4];
#pragma unroll
    for (int rt = 0; rt < 2; ++rt)
#pragma unroll
      for (int ct = 0; ct < 4; ++ct)
        oacc[rt][ct] = f32x4{0.f, 0.f, 0.f, 0.f};

    if (tid < 32) { m_s[tid] = NEG_INF; l_s[tid] = 0.0f; }
    if (tid == 0) resc_s = 0;
    BAR_ALL();   // tiles 0/1 staged

    for (int kt = 0; kt < nkt; ++kt) {
      const int cur = kt & 1;

      // ---- QK^T: wave (ti,kq) -> both 16x16 S-tiles over its k-eighth ----
      {
        f32x4 s0 = f32x4{0.f, 0.f, 0.f, 0.f};
        f32x4 s1 = f32x4{0.f, 0.f, 0.f, 0.f};
        const _Float16* kb = &Kbuf[cur][0];
#pragma unroll
        for (int s = 0; s < 4; ++s) {
          const int base = (kq * 8 + s * 2 + (lg >> 1)) * 512;
          half8 bf0 = *(const half8*)&kb[base + bk0];
          half8 bf1 = *(const half8*)&kb[base + bk1];
          s0 = mfma16(qf[s], bf0, s0);
          s1 = mfma16(qf[s], bf1, s1);
        }
#pragma unroll
        for (int j = 0; j < 4; ++j) {
          half2v pr2 = {(_Float16)s0[j], (_Float16)s1[j]};
          *(half2v*)&SredH[kq][ti * 16 + lg * 4 + j][lr][0] = pr2;
        }
      }
      BAR_LDS();   // (A) SredH ready — staging loads stay in flight

      // ---- online softmax: 16 lanes per q-row (waves 0..7 only) ----
      if (tid < 512) {
        const int r   = tid >> 4;
        const int c0  = tid & 15;
        const int qg  = qbase + r;
        const int kb0 = kt * 32;
        float s0 = 0.f, s1 = 0.f;
#pragma unroll
        for (int k8 = 0; k8 < 8; ++k8) {
          half2v v = *(const half2v*)&SredH[k8][r][c0][0];
          s0 += (float)v[0];
          s1 += (float)v[1];
        }
        s0 *= 0.03125f; s1 *= 0.03125f;
        const bool v0 = (kb0 + c0)      < qg;
        const bool v1 = (kb0 + c0 + 16) < qg;
        if (!v0) s0 = NEG_INF;
        if (!v1) s1 = NEG_INF;
        float tmax = fmaxf(s0, s1);
#pragma unroll
        for (int d = 1; d < 16; d <<= 1) tmax = fmaxf(tmax, __shfl_xor(tmax, d));
        const float m_old = m_s[r];
        const float m_new = fmaxf(m_old, tmax);
        float p0 = v0 ? __expf(s0 - m_new) : 0.0f;
        float p1 = v1 ? __expf(s1 - m_new) : 0.0f;
        float ps = p0 + p1;
#pragma unroll
        for (int d = 1; d < 16; d <<= 1) ps += __shfl_xor(ps, d);
        if (c0 == 0) {
          const float corr = (m_old > 0.5f * NEG_INF) ? __expf(m_old - m_new) : 0.0f;
          m_s[r]    = m_new;
          l_s[r]    = l_s[r] * corr + ps;
          corr_s[r] = corr;
          if (m_new > m_old) resc_s = 1;   // exact: corr==1 when not set
        }
        Pq[r][c0]      = (_Float16)p0;
        Pq[r][c0 + 16] = (_Float16)p1;
      }
      BAR_LDS();   // (B) Pq/corr/resc ready

      // ---- PV: optional rescale, then asm-pipelined tr_read + MFMA ----
      {
        const int doresc = resc_s;
        if (doresc) {
#pragma unroll
          for (int rt = 0; rt < 2; ++rt)
#pragma unroll
            for (int j = 0; j < 4; ++j) {
              const float cr2 = corr_s[rt * 16 + lg * 4 + j];
#pragma unroll
              for (int ct = 0; ct < 4; ++ct) oacc[rt][ct][j] *= cr2;
            }
        }
        const uint32_t pa0 = (uint32_t)(uintptr_t)(void*)&Pq[lr][lg * 8];
        const uint32_t pa1 = (uint32_t)(uintptr_t)(void*)&Pq[16 + lr][lg * 8];
        const uint32_t ab  = (uint32_t)(uintptr_t)(void*)&Kbuf[cur][w * 2048 + l * 4];
        // fence: no compiler LDS ops in flight inside the asm region
        asm volatile("s_waitcnt lgkmcnt(0)" ::: "memory");
        __builtin_amdgcn_sched_barrier(0);
        half8 a0, a1;
        half4v t0[4], t1[4];
        asm volatile("ds_read_b128 %0, %2\n\t"
                     "ds_read_b128 %1, %3"
                     : "=&v"(a0), "=&v"(a1) : "v"(pa0), "v"(pa1));
        ISSUE4(t0, "0", "512", "1024", "1536");
        ISSUE4(t1, "2048", "2560", "3072", "3584");
        asm volatile("s_waitcnt lgkmcnt(4)" ::: "memory");
        __builtin_amdgcn_sched_barrier(0);
        MFMA4(t0, 0, 1);
        asm volatile("s_waitcnt lgkmcnt(0)" ::: "memory");
        __builtin_amdgcn_sched_barrier(0);
        MFMA4(t1, 2, 3);
      }
      BAR_ALL();   // (C) Kbuf[cur] reads done; prior staging (tile kt+1) drained

      // ---- stage tile kt+2 into buf[cur] (in flight across next iter) ----
      if (kt + 2 < nkt) {
        if constexpr (WS) {
          const _Float16* tn = wsx + (size_t)(b * 64 + kt + 2) * 32768;
#pragma unroll
          for (int i = 0; i < 4; ++i)
            __builtin_amdgcn_global_load_lds(
                (const __attribute__((address_space(1))) void*)(tn + w * 2048 + i * 512 + l * 8),
                (__attribute__((address_space(3))) void*)(&Kbuf[cur][w * 2048 + i * 512]), 16, 0, 0);
        } else {
          const int skey = tid >> 5, sc = tid & 31;
          const float* kp = xb + (size_t)((kt + 2) * 32 + skey) * DN + sc * 4;
#pragma unroll
          for (int j = 0; j < 8; ++j) {
            const int f = sc * 4 + 128 * j;
            float4 v = *(const float4*)(kp + 128 * j);
            half4v h = {(_Float16)v.x, (_Float16)v.y, (_Float16)v.z, (_Float16)v.w};
            *(half4v*)&Kbuf[cur][img_off(skey, f)] = h;
          }
        }
      }
    }

    // ---- epilogue: per-row <x,O>, |x|^2, |O|^2 (per-wave 64-feat slice) ----
    {
      float* ered = (float*)&SredH[0][0][0][0];   // reuse 8KB of 17.4KB
#pragma unroll
      for (int rt = 0; rt < 2; ++rt)
#pragma unroll
        for (int j = 0; j < 4; ++j) {
          const int row = rt * 16 + lg * 4 + j;
          const float* xr = xb + (size_t)(qbase + row) * DN + w * 64 + lr;
          float a1 = 0.f, a2 = 0.f, a3 = 0.f;
#pragma unroll
          for (int ct = 0; ct < 4; ++ct) {
            const float xv = xr[ct * 16];
            const float ov = oacc[rt][ct][j];
            a1 += xv * ov; a2 += xv * xv; a3 += ov * ov;
          }
#pragma unroll
          for (int d = 1; d < 16; d <<= 1) {
            a1 += __shfl_xor(a1, d);
            a2 += __shfl_xor(a2, d);
            a3 += __shfl_xor(a3, d);
          }
          if (lr == 0) {
            float* e = ered + (row * 16 + w) * 4;
            e[0] = a1; e[1] = a2; e[2] = a3;
          }
        }
    }
    __syncthreads();
    if (tid < 32) {
      const float* ered = (const float*)&SredH[0][0][0][0];
      float SxO = 0.f, Sxx = 0.f, SOO = 0.f;
#pragma unroll
      for (int wv = 0; wv < 16; ++wv) {
        const float* e = ered + (tid * 16 + wv) * 4;
        SxO += e[0]; Sxx += e[1]; SOO += e[2];
      }
      const float lden = l_s[tid];
      float cosv = 0.0f;
      if (lden > 0.0f) {
        const float nx = fmaxf(sqrtf(Sxx), 1e-12f);
        const float nc = fmaxf(sqrtf(SOO) / lden, 1e-12f);
        cosv = (SxO / lden) / (nx * nc);
      }
      float nov = fminf(fmaxf(1.0f - cosv, 0.0f), 2.0f) * 0.5f;
      gate_s[tid] = 1.0f + alpha * tanhf(sigma * nov);
    }
    __syncthreads();
    {
#pragma unroll
      for (int rt = 0; rt < 2; ++rt)
#pragma unroll
        for (int j = 0; j < 4; ++j) {
          const int row = rt * 16 + lg * 4 + j;
          const float g = gate_s[row];
          const float* xr = xb + (size_t)(qbase + row) * DN + w * 64 + lr;
          float* orow     = ob + (size_t)(qbase + row) * DN + w * 64 + lr;
#pragma unroll
          for (int ct = 0; ct < 4; ++ct) {
            const float z = xr[ct * 16] * g;
            const float u = 0.7978845608028654f * (z + 0.044715f * z * z * z);
            orow[ct * 16] = 0.5f * z * (1.0f + tanhf(u));
          }
        }
    }
    __syncthreads();
  }
}

extern "C" void kernel_launch(void* const* d_in, const int* in_sizes, int n_in,
                              void* d_out, int out_size, void* d_ws, size_t ws_size,
                              hipStream_t stream) {
  const float* x  = (const float*)d_in[0];
  const float* la = (const float*)d_in[1];
  const float* ls = (const float*)d_in[2];
  float* out = (float*)d_out;
  const size_t need = (size_t)8 * 64 * 32768 * 2;   // 32 MB f16 tile images
  if (ws_size >= need) {
    convert_x<<<dim3(8192), dim3(256), 0, stream>>>(x, (_Float16*)d_ws);
    attn_gate<true><<<dim3(256), dim3(1024), 0, stream>>>(
        x, (const _Float16*)d_ws, la, ls, out);
  } else {
    attn_gate<false><<<dim3(256), dim3(1024), 0, stream>>>(
        x, (const _Float16*)nullptr, la, ls, out);
  }
}

// Round 7
// 203.656 us; speedup vs baseline: 1.4722x; 1.0675x over previous
//
#include <hip/hip_runtime.h>
#include <math.h>

#define TN 2048
#define DN 1024
#define NEG_INF (-3.0e38f)

typedef __attribute__((ext_vector_type(8))) _Float16 half8;
typedef __attribute__((ext_vector_type(4))) _Float16 half4v;
typedef __attribute__((ext_vector_type(2))) _Float16 half2v;
typedef __attribute__((ext_vector_type(4))) float f32x4;

__device__ __forceinline__ f32x4 mfma16(half8 a, half8 b, f32x4 c) {
  return __builtin_amdgcn_mfma_f32_16x16x32_f16(a, b, c, 0, 0, 0);
}

// lgkm-only barrier (async staging survives); BAR_ALL drains vmcnt too.
#define BAR_LDS()  asm volatile("s_waitcnt lgkmcnt(0)\ns_barrier" ::: "memory")
#define BAR_ALL()  asm volatile("s_waitcnt vmcnt(0) lgkmcnt(0)\ns_barrier" ::: "memory")

// Tile image layout (32 keys x 1024 feats, f16, 64KB):
//   elem_off(key,f) = (f>>4)*512 + perm(key>>2)*64 + (key&3)*16 + (f&15)
//   perm(kg) = (kg&1)*4 + (kg>>1)   (tr_read lane-group lg sees keys 8*lg+j)
__device__ __forceinline__ int img_off(int key, int f) {
  const int kg = key >> 2;
  const int p  = ((kg & 1) << 2) | (kg >> 1);
  return (f >> 4) * 512 + p * 64 + (key & 3) * 16 + (f & 15);
}

// x fp32 [8][2048][1024] -> f16 tile images in ws: [b*64+tile][32768 elems]
__global__ __launch_bounds__(256) void convert_x(const float* __restrict__ x,
                                                 _Float16* __restrict__ w) {
  const long long gid = (long long)blockIdx.x * 256 + threadIdx.x;
  const long long e   = gid * 8;
  const int bt   = (int)(e >> 15);
  const int et   = (int)(e & 32767);
  const int f16b = et >> 9;
  const int p    = (et >> 6) & 7;
  const int row  = (et >> 4) & 3;
  const int col0 = et & 15;
  const int kg   = ((p & 3) << 1) | (p >> 2);    // inverse perm
  const int key  = kg * 4 + row;
  const size_t xoff = ((size_t)bt * 32 + key) * DN + f16b * 16 + col0;
  float4 u0 = *(const float4*)(x + xoff);
  float4 u1 = *(const float4*)(x + xoff + 4);
  half8 h = {(_Float16)u0.x, (_Float16)u0.y, (_Float16)u0.z, (_Float16)u0.w,
             (_Float16)u1.x, (_Float16)u1.y, (_Float16)u1.z, (_Float16)u1.w};
  *(half8*)(w + e) = h;
}

#define ISSUE4(T, O0, O1, O2, O3)                                             \
  asm volatile("ds_read_b64_tr_b16 %0, %4 offset:" O0 "\n\t"                  \
               "ds_read_b64_tr_b16 %1, %4 offset:" O1 "\n\t"                  \
               "ds_read_b64_tr_b16 %2, %4 offset:" O2 "\n\t"                  \
               "ds_read_b64_tr_b16 %3, %4 offset:" O3                         \
               : "=&v"(T[0]), "=&v"(T[1]), "=&v"(T[2]), "=&v"(T[3])           \
               : "v"(ab));

#define MFMA4(T, CT0, CT1)                                                    \
  {                                                                           \
    half8 bf0 = __builtin_shufflevector(T[0], T[1], 0, 1, 2, 3, 4, 5, 6, 7);  \
    half8 bf1 = __builtin_shufflevector(T[2], T[3], 0, 1, 2, 3, 4, 5, 6, 7);  \
    oacc[0][CT0] = mfma16(a0, bf0, oacc[0][CT0]);                             \
    oacc[1][CT0] = mfma16(a1, bf0, oacc[1][CT0]);                             \
    oacc[0][CT1] = mfma16(a0, bf1, oacc[0][CT1]);                             \
    oacc[1][CT1] = mfma16(a1, bf1, oacc[1][CT1]);                             \
  }

// One block = (batch, pair {pr,63-pr}) via hv loop -> 65 iters/block.
// 8 waves, pure 8-way k-split: wave kq computes ALL FOUR 16x16 S-tiles over
// its 128-feat slice (4 MFMA per bf0/bf1 read pair) -> K tile read exactly
// once per iter for QK (64 ds_read_b128, half of R3/R6's 128).
template <bool WS>
__global__ __launch_bounds__(512)
void attn_gate(const float* __restrict__ x, const _Float16* __restrict__ wsx,
               const float* __restrict__ pla, const float* __restrict__ pls,
               float* __restrict__ out) {
  __shared__ _Float16 Kbuf[2][32768];         // dbuf K tile images    128KB
  __shared__ _Float16 SredH[8][32][17][2];    // packed S partials     17.4KB
  __shared__ _Float16 Pq[32][40];             // P weights             2.5KB
  __shared__ float m_s[32], l_s[32], corr_s[32], gate_s[32];
  __shared__ int resc_s;

  const int tid = threadIdx.x;
  const int w   = tid >> 6;       // wave 0..7 == kq (k-eighth, 128 feats)
  const int l   = tid & 63;
  const int lr  = l & 15;
  const int lg  = l >> 4;
  const int kq  = w;

  const int b  = blockIdx.x & 7;          // batch -> XCD
  const int pr = blockIdx.x >> 3;         // pair 0..31

  const float alpha = log1pf(expf(pla[0]));
  const float sigma = log1pf(expf(pls[0]));

  const float* xb = x + (size_t)b * TN * DN;
  float*       ob = out + (size_t)b * TN * DN;

  // QK B-frag bases (loop-invariant): keys lr and 16+lr
  const int kg0 = lr >> 2;
  const int bk0 = ((((kg0 & 1) << 2) | (kg0 >> 1)) << 6) + (lr & 3) * 16 + (lg & 1) * 8;
  const int kg1 = 4 + (lr >> 2);
  const int bk1 = ((((kg1 & 1) << 2) | (kg1 >> 1)) << 6) + (lr & 3) * 16 + (lg & 1) * 8;

  for (int hv = 0; hv < 2; ++hv) {
    const int qt    = hv ? (63 - pr) : pr;
    const int qbase = qt * 32;
    const int nkt   = qt + 1;

    // ---- stage tiles 0 (and 1) ----
    if constexpr (WS) {
      const _Float16* t0 = wsx + (size_t)(b * 64 + 0) * 32768;
#pragma unroll
      for (int i = 0; i < 8; ++i)
        __builtin_amdgcn_global_load_lds(
            (const __attribute__((address_space(1))) void*)(t0 + w * 4096 + i * 512 + l * 8),
            (__attribute__((address_space(3))) void*)(&Kbuf[0][w * 4096 + i * 512]), 16, 0, 0);
      if (nkt > 1) {
        const _Float16* t1 = wsx + (size_t)(b * 64 + 1) * 32768;
#pragma unroll
        for (int i = 0; i < 8; ++i)
          __builtin_amdgcn_global_load_lds(
              (const __attribute__((address_space(1))) void*)(t1 + w * 4096 + i * 512 + l * 8),
              (__attribute__((address_space(3))) void*)(&Kbuf[1][w * 4096 + i * 512]), 16, 0, 0);
      }
    } else {
      const int skey = tid >> 4, sc = tid & 15;
      for (int t = 0; t < (nkt > 1 ? 2 : 1); ++t) {
        const float* kp = xb + (size_t)(t * 32 + skey) * DN + sc * 4;
#pragma unroll
        for (int j = 0; j < 16; ++j) {
          const int f = sc * 4 + 64 * j;
          float4 v = *(const float4*)(kp + 64 * j);
          half4v h = {(_Float16)v.x, (_Float16)v.y, (_Float16)v.z, (_Float16)v.w};
          *(half4v*)&Kbuf[t][img_off(skey, f)] = h;
        }
      }
    }

    // ---- Q fragments: BOTH row-tiles over k-eighth (2x4 half8 = 32 VGPR) ----
    half8 qf0[4], qf1[4];
    if constexpr (WS) {
      const _Float16* qtile = wsx + (size_t)(b * 64 + qt) * 32768;
      const int r0  = lr;            // ti=0 row
      const int g0  = r0 >> 2;
      const int qp0 = (((g0 & 1) << 2) | (g0 >> 1)) * 64 + (r0 & 3) * 16 + (lg & 1) * 8;
      const int r1  = 16 + lr;       // ti=1 row
      const int g1  = r1 >> 2;
      const int qp1 = (((g1 & 1) << 2) | (g1 >> 1)) * 64 + (r1 & 3) * 16 + (lg & 1) * 8;
#pragma unroll
      for (int s = 0; s < 4; ++s) {
        const int base = (kq * 8 + s * 2 + (lg >> 1)) * 512;
        qf0[s] = *(const half8*)&qtile[base + qp0];
        qf1[s] = *(const half8*)&qtile[base + qp1];
      }
    } else {
#pragma unroll
      for (int s = 0; s < 4; ++s) {
        const float* qp0 = xb + (size_t)(qbase + lr) * DN + kq * 128 + s * 32 + lg * 8;
        const float* qp1 = xb + (size_t)(qbase + 16 + lr) * DN + kq * 128 + s * 32 + lg * 8;
        float4 a = ((const float4*)qp0)[0];
        float4 c = ((const float4*)qp0)[1];
        half8 h0;
        h0[0]=(_Float16)a.x; h0[1]=(_Float16)a.y; h0[2]=(_Float16)a.z; h0[3]=(_Float16)a.w;
        h0[4]=(_Float16)c.x; h0[5]=(_Float16)c.y; h0[6]=(_Float16)c.z; h0[7]=(_Float16)c.w;
        qf0[s] = h0;
        a = ((const float4*)qp1)[0];
        c = ((const float4*)qp1)[1];
        half8 h1;
        h1[0]=(_Float16)a.x; h1[1]=(_Float16)a.y; h1[2]=(_Float16)a.z; h1[3]=(_Float16)a.w;
        h1[4]=(_Float16)c.x; h1[5]=(_Float16)c.y; h1[6]=(_Float16)c.z; h1[7]=(_Float16)c.w;
        qf1[s] = h1;
      }
    }

    f32x4 oacc[2][8];
#pragma unroll
    for (int rt = 0; rt < 2; ++rt)
#pragma unroll
      for (int ct = 0; ct < 8; ++ct)
        oacc[rt][ct] = f32x4{0.f, 0.f, 0.f, 0.f};

    if (tid < 32) { m_s[tid] = NEG_INF; l_s[tid] = 0.0f; }
    if (tid == 0) resc_s = 0;
    BAR_ALL();   // tiles 0/1 staged

    for (int kt = 0; kt < nkt; ++kt) {
      const int cur = kt & 1;

      // ---- QK^T: wave kq -> all four 16x16 S-tiles over its k-eighth ----
      {
        f32x4 s00 = f32x4{0.f,0.f,0.f,0.f}, s01 = f32x4{0.f,0.f,0.f,0.f};
        f32x4 s10 = f32x4{0.f,0.f,0.f,0.f}, s11 = f32x4{0.f,0.f,0.f,0.f};
        const _Float16* kb = &Kbuf[cur][0];
#pragma unroll
        for (int s = 0; s < 4; ++s) {
          const int base = (kq * 8 + s * 2 + (lg >> 1)) * 512;
          half8 bf0 = *(const half8*)&kb[base + bk0];
          half8 bf1 = *(const half8*)&kb[base + bk1];
          s00 = mfma16(qf0[s], bf0, s00);
          s10 = mfma16(qf1[s], bf0, s10);
          s01 = mfma16(qf0[s], bf1, s01);
          s11 = mfma16(qf1[s], bf1, s11);
        }
#pragma unroll
        for (int j = 0; j < 4; ++j) {
          half2v p0 = {(_Float16)s00[j], (_Float16)s01[j]};
          *(half2v*)&SredH[kq][lg * 4 + j][lr][0] = p0;
          half2v p1 = {(_Float16)s10[j], (_Float16)s11[j]};
          *(half2v*)&SredH[kq][16 + lg * 4 + j][lr][0] = p1;
        }
      }
      BAR_LDS();   // (A) SredH ready — staging loads stay in flight

      // ---- online softmax: 16 lanes per q-row ----
      {
        const int r   = tid >> 4;
        const int c0  = tid & 15;
        const int qg  = qbase + r;
        const int kb0 = kt * 32;
        float s0 = 0.f, s1 = 0.f;
#pragma unroll
        for (int k8 = 0; k8 < 8; ++k8) {
          half2v v = *(const half2v*)&SredH[k8][r][c0][0];
          s0 += (float)v[0];
          s1 += (float)v[1];
        }
        s0 *= 0.03125f; s1 *= 0.03125f;
        const bool v0 = (kb0 + c0)      < qg;
        const bool v1 = (kb0 + c0 + 16) < qg;
        if (!v0) s0 = NEG_INF;
        if (!v1) s1 = NEG_INF;
        float tmax = fmaxf(s0, s1);
#pragma unroll
        for (int d = 1; d < 16; d <<= 1) tmax = fmaxf(tmax, __shfl_xor(tmax, d));
        const float m_old = m_s[r];
        const float m_new = fmaxf(m_old, tmax);
        float p0 = v0 ? __expf(s0 - m_new) : 0.0f;
        float p1 = v1 ? __expf(s1 - m_new) : 0.0f;
        float ps = p0 + p1;
#pragma unroll
        for (int d = 1; d < 16; d <<= 1) ps += __shfl_xor(ps, d);
        if (c0 == 0) {
          const float corr = (m_old > 0.5f * NEG_INF) ? __expf(m_old - m_new) : 0.0f;
          m_s[r]    = m_new;
          l_s[r]    = l_s[r] * corr + ps;
          corr_s[r] = corr;
          if (m_new > m_old) resc_s = 1;   // exact: corr==1 when not set
        }
        Pq[r][c0]      = (_Float16)p0;
        Pq[r][c0 + 16] = (_Float16)p1;
      }
      BAR_LDS();   // (B) Pq/corr/resc ready

      // ---- PV: optional rescale, then asm-pipelined tr_read + MFMA ----
      {
        const int doresc = resc_s;
        if (doresc) {
#pragma unroll
          for (int rt = 0; rt < 2; ++rt)
#pragma unroll
            for (int j = 0; j < 4; ++j) {
              const float cr2 = corr_s[rt * 16 + lg * 4 + j];
#pragma unroll
              for (int ct = 0; ct < 8; ++ct) oacc[rt][ct][j] *= cr2;
            }
        }
        const uint32_t pa0 = (uint32_t)(uintptr_t)(void*)&Pq[lr][lg * 8];
        const uint32_t pa1 = (uint32_t)(uintptr_t)(void*)&Pq[16 + lr][lg * 8];
        const uint32_t ab  = (uint32_t)(uintptr_t)(void*)&Kbuf[cur][w * 4096 + l * 4];
        // fence: no compiler LDS ops in flight inside the asm region
        asm volatile("s_waitcnt lgkmcnt(0)" ::: "memory");
        __builtin_amdgcn_sched_barrier(0);
        half8 a0, a1;
        half4v t0[4], t1[4];
        asm volatile("ds_read_b128 %0, %2\n\t"
                     "ds_read_b128 %1, %3"
                     : "=&v"(a0), "=&v"(a1) : "v"(pa0), "v"(pa1));
        ISSUE4(t0, "0", "512", "1024", "1536");
        ISSUE4(t1, "2048", "2560", "3072", "3584");
        asm volatile("s_waitcnt lgkmcnt(4)" ::: "memory");
        __builtin_amdgcn_sched_barrier(0);
        MFMA4(t0, 0, 1);
        ISSUE4(t0, "4096", "4608", "5120", "5632");
        asm volatile("s_waitcnt lgkmcnt(4)" ::: "memory");
        __builtin_amdgcn_sched_barrier(0);
        MFMA4(t1, 2, 3);
        ISSUE4(t1, "6144", "6656", "7168", "7680");
        asm volatile("s_waitcnt lgkmcnt(4)" ::: "memory");
        __builtin_amdgcn_sched_barrier(0);
        MFMA4(t0, 4, 5);
        asm volatile("s_waitcnt lgkmcnt(0)" ::: "memory");
        __builtin_amdgcn_sched_barrier(0);
        MFMA4(t1, 6, 7);
      }
      BAR_ALL();   // (C) Kbuf[cur] free; staging of tile kt+1 complete

      // ---- stage tile kt+2 into buf[cur] (in flight across next iter) ----
      if (kt + 2 < nkt) {
        if constexpr (WS) {
          const _Float16* tn = wsx + (size_t)(b * 64 + kt + 2) * 32768;
#pragma unroll
          for (int i = 0; i < 8; ++i)
            __builtin_amdgcn_global_load_lds(
                (const __attribute__((address_space(1))) void*)(tn + w * 4096 + i * 512 + l * 8),
                (__attribute__((address_space(3))) void*)(&Kbuf[cur][w * 4096 + i * 512]), 16, 0, 0);
        } else {
          const int skey = tid >> 4, sc = tid & 15;
          const float* kp = xb + (size_t)((kt + 2) * 32 + skey) * DN + sc * 4;
#pragma unroll
          for (int j = 0; j < 16; ++j) {
            const int f = sc * 4 + 64 * j;
            float4 v = *(const float4*)(kp + 64 * j);
            half4v h = {(_Float16)v.x, (_Float16)v.y, (_Float16)v.z, (_Float16)v.w};
            *(half4v*)&Kbuf[cur][img_off(skey, f)] = h;
          }
        }
      }
    }

    // ---- epilogue: per-row <x,O>, |x|^2, |O|^2 (per-wave 128-feat slice) ----
    {
      float* ered = (float*)&SredH[0][0][0][0];   // reuse 4KB
#pragma unroll
      for (int rt = 0; rt < 2; ++rt)
#pragma unroll
        for (int j = 0; j < 4; ++j) {
          const int row = rt * 16 + lg * 4 + j;
          const float* xr = xb + (size_t)(qbase + row) * DN + w * 128 + lr;
          float a1 = 0.f, a2 = 0.f, a3 = 0.f;
#pragma unroll
          for (int ct = 0; ct < 8; ++ct) {
            const float xv = xr[ct * 16];
            const float ov = oacc[rt][ct][j];
            a1 += xv * ov; a2 += xv * xv; a3 += ov * ov;
          }
#pragma unroll
          for (int d = 1; d < 16; d <<= 1) {
            a1 += __shfl_xor(a1, d);
            a2 += __shfl_xor(a2, d);
            a3 += __shfl_xor(a3, d);
          }
          if (lr == 0) {
            float* e = ered + (row * 8 + w) * 4;
            e[0] = a1; e[1] = a2; e[2] = a3;
          }
        }
    }
    __syncthreads();
    if (tid < 32) {
      const float* ered = (const float*)&SredH[0][0][0][0];
      float SxO = 0.f, Sxx = 0.f, SOO = 0.f;
#pragma unroll
      for (int wv = 0; wv < 8; ++wv) {
        const float* e = ered + (tid * 8 + wv) * 4;
        SxO += e[0]; Sxx += e[1]; SOO += e[2];
      }
      const float lden = l_s[tid];
      float cosv = 0.0f;
      if (lden > 0.0f) {
        const float nx = fmaxf(sqrtf(Sxx), 1e-12f);
        const float nc = fmaxf(sqrtf(SOO) / lden, 1e-12f);
        cosv = (SxO / lden) / (nx * nc);
      }
      float nov = fminf(fmaxf(1.0f - cosv, 0.0f), 2.0f) * 0.5f;
      gate_s[tid] = 1.0f + alpha * tanhf(sigma * nov);
    }
    __syncthreads();
    {
#pragma unroll
      for (int rt = 0; rt < 2; ++rt)
#pragma unroll
        for (int j = 0; j < 4; ++j) {
          const int row = rt * 16 + lg * 4 + j;
          const float g = gate_s[row];
          const float* xr = xb + (size_t)(qbase + row) * DN + w * 128 + lr;
          float* orow     = ob + (size_t)(qbase + row) * DN + w * 128 + lr;
#pragma unroll
          for (int ct = 0; ct < 8; ++ct) {
            const float z = xr[ct * 16] * g;
            const float u = 0.7978845608028654f * (z + 0.044715f * z * z * z);
            orow[ct * 16] = 0.5f * z * (1.0f + tanhf(u));
          }
        }
    }
    __syncthreads();
  }
}

extern "C" void kernel_launch(void* const* d_in, const int* in_sizes, int n_in,
                              void* d_out, int out_size, void* d_ws, size_t ws_size,
                              hipStream_t stream) {
  const float* x  = (const float*)d_in[0];
  const float* la = (const float*)d_in[1];
  const float* ls = (const float*)d_in[2];
  float* out = (float*)d_out;
  const size_t need = (size_t)8 * 64 * 32768 * 2;   // 32 MB f16 tile images
  if (ws_size >= need) {
    convert_x<<<dim3(8192), dim3(256), 0, stream>>>(x, (_Float16*)d_ws);
    attn_gate<true><<<dim3(256), dim3(512), 0, stream>>>(
        x, (const _Float16*)d_ws, la, ls, out);
  } else {
    attn_gate<false><<<dim3(256), dim3(512), 0, stream>>>(
        x, (const _Float16*)nullptr, la, ls, out);
  }
}